// Round 10
// baseline (1325.009 us; speedup 1.0000x reference)
//
#include <hip/hip_runtime.h>
#include <hip/hip_bf16.h>

// Problem constants
#define T_TOKENS 4096      // B*S
#define DIM      1024
#define HID      4096
#define NE       8
#define CAP      4096      // max tokens per expert
#define SPLITS   4         // split-K factor for ffn2
#define KSP      (HID / SPLITS)   // 1024

typedef __attribute__((ext_vector_type(8))) short  bf16x8;
typedef __attribute__((ext_vector_type(4))) float  f32x4;
typedef __attribute__((ext_vector_type(4))) ushort u16x4;

__device__ static inline ushort f2bf(float f) {
    __hip_bfloat16 h = __float2bfloat16(f);
    return *(ushort*)&h;
}

// async global -> LDS, 16 bytes per lane. LDS dest = wave-uniform base +
// lane*16 (linear). Swizzle applied on the GLOBAL source address.
__device__ static inline void gll16(const void* g, void* l) {
    __builtin_amdgcn_global_load_lds(
        (const __attribute__((address_space(1))) void*)g,
        (__attribute__((address_space(3))) void*)l,
        16, 0, 0);
}

#define MFMA16(a, b, c) __builtin_amdgcn_mfma_f32_16x16x32_bf16((a), (b), (c), 0, 0, 0)

// ---------------------------------------------------------------------------
// Gate: logits -> top2 -> softmax -> per-expert token lists; also x -> bf16.
// ---------------------------------------------------------------------------
__global__ __launch_bounds__(64) void gate_kernel(
    const float* __restrict__ x, const float* __restrict__ gw,
    const float* __restrict__ gb, __hip_bfloat16* __restrict__ xb,
    int* __restrict__ counts, int* __restrict__ tlist, float* __restrict__ plist)
{
    const int tok = blockIdx.x;
    const int l   = threadIdx.x;
    const float* xr = x + (size_t)tok * DIM;

    float part[NE];
#pragma unroll
    for (int e = 0; e < NE; e++) part[e] = 0.f;

#pragma unroll
    for (int i = 0; i < DIM / 64; i++) {
        int d = i * 64 + l;
        float xv = xr[d];
        xb[(size_t)tok * DIM + d] = __float2bfloat16(xv);
        const float4* g4 = (const float4*)(gw + (size_t)d * NE);
        float4 a = g4[0], b = g4[1];
        part[0] += xv * a.x; part[1] += xv * a.y;
        part[2] += xv * a.z; part[3] += xv * a.w;
        part[4] += xv * b.x; part[5] += xv * b.y;
        part[6] += xv * b.z; part[7] += xv * b.w;
    }
#pragma unroll
    for (int off = 32; off > 0; off >>= 1) {
#pragma unroll
        for (int e = 0; e < NE; e++) part[e] += __shfl_xor(part[e], off, 64);
    }
    if (l == 0) {
        float lg[NE];
#pragma unroll
        for (int e = 0; e < NE; e++) lg[e] = part[e] + gb[e];
        int i0 = 0;
#pragma unroll
        for (int e = 1; e < NE; e++) if (lg[e] > lg[i0]) i0 = e;   // lowest idx on tie
        int i1 = (i0 == 0) ? 1 : 0;
#pragma unroll
        for (int e = 0; e < NE; e++) if (e != i0 && lg[e] > lg[i1]) i1 = e;
        float t  = expf(lg[i1] - lg[i0]);
        float p0 = 1.f / (1.f + t);
        float p1 = t / (1.f + t);
        int pos0 = atomicAdd(&counts[i0], 1);
        tlist[i0 * CAP + pos0] = tok; plist[i0 * CAP + pos0] = p0;
        int pos1 = atomicAdd(&counts[i1], 1);
        tlist[i1 * CAP + pos1] = tok; plist[i1 * CAP + pos1] = p1;
    }
}

// ---------------------------------------------------------------------------
// finalize: prefix-sum bases + build global task lists (expert-major,
// rb-major inner).
// ---------------------------------------------------------------------------
__global__ void finalize_kernel(const int* __restrict__ counts, int* __restrict__ base,
                                int* __restrict__ task1, int* __restrict__ task2,
                                int* __restrict__ ntasks)
{
    __shared__ int stc[NE], so1[NE], so2[NE];
    if (threadIdx.x == 0) {
        int acc = 0, o1 = 0, o2 = 0;
        for (int e = 0; e < NE; e++) {
            base[e] = acc; acc += counts[e];
            int tc = (counts[e] + 255) >> 8;
            stc[e] = tc; so1[e] = o1; so2[e] = o2;
            o1 += tc * 16; o2 += tc * 16;
        }
        base[NE] = acc;
        ntasks[0] = o1; ntasks[1] = o2;
    }
    __syncthreads();
    for (int e = 0; e < NE; e++) {
        int tc = stc[e];
        for (int i = threadIdx.x; i < tc * 16; i += 64) {
            int rb = i >> 4, cb = i & 15;
            task1[so1[e] + i] = (e << 16) | (rb << 8) | cb;
        }
        for (int i = threadIdx.x; i < tc * 16; i += 64) {
            int rb = i >> 4, c = i & 15;      // c = cb*4+sp
            task2[so2[e] + i] = (e << 16) | (rb << 8) | c;
        }
    }
}

// ---------------------------------------------------------------------------
// Transpose + f32->bf16 convert:  in [E][K][N] f32  ->  out [E][N][K] bf16
// ---------------------------------------------------------------------------
__global__ __launch_bounds__(256) void transpose_cvt64(
    const float* __restrict__ in, __hip_bfloat16* __restrict__ outp, int K, int N)
{
    __shared__ ushort tile[64][68];
    const int e  = blockIdx.z;
    const float* src = in + (size_t)e * K * N;
    ushort* dst = (ushort*)outp + (size_t)e * K * N;
    const int k0 = blockIdx.y * 64, n0 = blockIdx.x * 64;
    const int tid = threadIdx.x;

    const int rn4 = (tid & 15) * 4;
    const int rk  = tid >> 4;
#pragma unroll
    for (int p = 0; p < 4; p++) {
        int k = rk + p * 16;
        float4 v = *(const float4*)&src[(size_t)(k0 + k) * N + n0 + rn4];
        tile[k][rn4 + 0] = f2bf(v.x);
        tile[k][rn4 + 1] = f2bf(v.y);
        tile[k][rn4 + 2] = f2bf(v.z);
        tile[k][rn4 + 3] = f2bf(v.w);
    }
    __syncthreads();
    const int wk4 = (tid & 15) * 4;
    const int wn  = tid >> 4;
#pragma unroll
    for (int p = 0; p < 4; p++) {
        int n = wn + p * 16;
        u16x4 u;
        u[0] = tile[wk4 + 0][n];
        u[1] = tile[wk4 + 1][n];
        u[2] = tile[wk4 + 2][n];
        u[3] = tile[wk4 + 3][n];
        *(u16x4*)&dst[(size_t)(n0 + n) * K + k0 + wk4] = u;
    }
}

// ===========================================================================
// 256x256 8-phase grouped GEMM core. KMUL: 1 = real K-walk, 0 = all staging
// re-reads offset-0 (L2/L1-resident diagnostic). STAGE: 0 = no gll16 at all
// (skeleton diagnostic; vmcnt waits become no-ops with nothing outstanding).
// ===========================================================================

#define AOFFc(d,s) (((d)*2+(s))*8192)
#define BOFFc(d,s) (32768 + ((d)*2+(s))*8192)

#define MFMA_CL(nj0, nj1)                                                    \
    _Pragma("unroll")                                                        \
    for (int mi = 0; mi < 8; mi++) {                                         \
        acc[mi][nj0] = MFMA16(af[mi], bf##nj0, acc[mi][nj0]);                \
        acc[mi][nj1] = MFMA16(af[mi], bf##nj1, acc[mi][nj1]);                \
    }

#define GEMM_CORE_V(NT, srcA0, srcA1, srcB0, srcB1, KMUL, STAGE)             \
    f32x4 acc[8][4];                                                         \
    _Pragma("unroll")                                                        \
    for (int i = 0; i < 8; i++)                                              \
        _Pragma("unroll")                                                    \
        for (int j = 0; j < 4; j++) acc[i][j] = (f32x4){0.f,0.f,0.f,0.f};    \
    const int a0 = (wr * 128 + lm) * 32 + rch;                               \
    const int b0 = (wc * 64 + lm) * 32 + rch;                                \
    if (STAGE) {                                                             \
        gll16(srcA0,             &lds[AOFFc(0,0) + w*512]);                  \
        gll16(srcA1,             &lds[AOFFc(0,0) + 4096 + w*512]);           \
        gll16(srcB0,             &lds[BOFFc(0,0) + w*512]);                  \
        gll16(srcB1,             &lds[BOFFc(0,0) + 4096 + w*512]);           \
        gll16(srcA0 + 32*KMUL,   &lds[AOFFc(0,1) + w*512]);                  \
        gll16(srcA1 + 32*KMUL,   &lds[AOFFc(0,1) + 4096 + w*512]);           \
        gll16(srcB0 + 32*KMUL,   &lds[BOFFc(0,1) + w*512]);                  \
        gll16(srcB1 + 32*KMUL,   &lds[BOFFc(0,1) + 4096 + w*512]);           \
        asm volatile("s_waitcnt vmcnt(4)" ::: "memory");                     \
        gll16(srcA0 + 64*KMUL,   &lds[AOFFc(1,0) + w*512]);                  \
        gll16(srcA1 + 64*KMUL,   &lds[AOFFc(1,0) + 4096 + w*512]);           \
        gll16(srcB0 + 64*KMUL,   &lds[BOFFc(1,0) + w*512]);                  \
        gll16(srcB1 + 64*KMUL,   &lds[BOFFc(1,0) + 4096 + w*512]);           \
        gll16(srcA0 + 96*KMUL,   &lds[AOFFc(1,1) + w*512]);                  \
        gll16(srcA1 + 96*KMUL,   &lds[AOFFc(1,1) + 4096 + w*512]);           \
        asm volatile("s_waitcnt vmcnt(6)" ::: "memory");                     \
    }                                                                        \
    __builtin_amdgcn_s_barrier();                                            \
    _Pragma("unroll 1")                                                      \
    for (int t = 0; t < NT; t++) {                                           \
        const int d   = t & 1;                                               \
        const int aof  = d * 16384,        bof  = 32768 + d * 16384;         \
        const int bofN = 32768 + (d^1) * 16384;                              \
        bf16x8 af[8]; bf16x8 bf0, bf1, bf2, bf3;                             \
        _Pragma("unroll")                                                    \
        for (int mi = 0; mi < 8; mi++)                                       \
            af[mi] = *(const bf16x8*)&lds[aof + a0 + mi*512];                \
        bf0 = *(const bf16x8*)&lds[bof + b0];                                \
        bf1 = *(const bf16x8*)&lds[bof + b0 + 512];                          \
        if (STAGE && t + 1 < NT) {                                           \
            size_t ko = (size_t)((t+1)*64 + 32) * KMUL;                      \
            gll16(srcB0 + ko, &lds[bofN + 8192 + w*512]);                    \
            gll16(srcB1 + ko, &lds[bofN + 8192 + 4096 + w*512]);             \
        }                                                                    \
        __builtin_amdgcn_s_barrier();                                        \
        __builtin_amdgcn_s_setprio(1);                                       \
        MFMA_CL(0, 1)                                                        \
        __builtin_amdgcn_s_setprio(0);                                       \
        __builtin_amdgcn_s_barrier();                                        \
        bf2 = *(const bf16x8*)&lds[bof + b0 + 1024];                         \
        bf3 = *(const bf16x8*)&lds[bof + b0 + 1536];                         \
        if (STAGE && t + 2 < NT) {                                           \
            size_t ko = (size_t)((t+2)*64) * KMUL;                           \
            gll16(srcA0 + ko, &lds[aof + w*512]);                            \
            gll16(srcA1 + ko, &lds[aof + 4096 + w*512]);                     \
        }                                                                    \
        __builtin_amdgcn_s_barrier();                                        \
        __builtin_amdgcn_s_setprio(1);                                       \
        MFMA_CL(2, 3)                                                        \
        __builtin_amdgcn_s_setprio(0);                                       \
        __builtin_amdgcn_s_barrier();                                        \
        _Pragma("unroll")                                                    \
        for (int mi = 0; mi < 8; mi++)                                       \
            af[mi] = *(const bf16x8*)&lds[aof + 8192 + a0 + mi*512];         \
        bf0 = *(const bf16x8*)&lds[bof + 8192 + b0];                         \
        bf1 = *(const bf16x8*)&lds[bof + 8192 + b0 + 512];                   \
        if (STAGE && t + 2 < NT) {                                           \
            size_t ko = (size_t)((t+2)*64) * KMUL;                           \
            gll16(srcB0 + ko, &lds[bof + w*512]);                            \
            gll16(srcB1 + ko, &lds[bof + 4096 + w*512]);                     \
        }                                                                    \
        __builtin_amdgcn_s_barrier();                                        \
        __builtin_amdgcn_s_setprio(1);                                       \
        MFMA_CL(0, 1)                                                        \
        __builtin_amdgcn_s_setprio(0);                                       \
        __builtin_amdgcn_s_barrier();                                        \
        bf2 = *(const bf16x8*)&lds[bof + 8192 + b0 + 1024];                  \
        bf3 = *(const bf16x8*)&lds[bof + 8192 + b0 + 1536];                  \
        if (STAGE && t + 2 < NT) {                                           \
            size_t ko = (size_t)((t+2)*64 + 32) * KMUL;                      \
            gll16(srcA0 + ko, &lds[aof + 8192 + w*512]);                     \
            gll16(srcA1 + ko, &lds[aof + 8192 + 4096 + w*512]);              \
        }                                                                    \
        __builtin_amdgcn_s_barrier();                                        \
        __builtin_amdgcn_s_setprio(1);                                       \
        MFMA_CL(2, 3)                                                        \
        __builtin_amdgcn_s_setprio(0);                                       \
        if (STAGE) {                                                         \
            if (t < NT - 2) { asm volatile("s_waitcnt vmcnt(6)" ::: "memory"); } \
            else            { asm volatile("s_waitcnt vmcnt(0)" ::: "memory"); } \
        }                                                                    \
        __builtin_amdgcn_s_barrier();                                        \
    }

#define GEMM_CORE(NT, a, b, c, dd) GEMM_CORE_V(NT, a, b, c, dd, 1, 1)

// Common per-thread index setup for all 256^2 core kernels
#define CORE_IDX                                                             \
    const int tid = threadIdx.x;                                             \
    const int l = tid & 63, w = tid >> 6;                                    \
    const int wr = w >> 2, wc = w & 3;                                       \
    const int lm = l & 15, kg = l >> 4;                                      \
    const int rch = (kg ^ ((lm >> 1) & 3)) * 8;                              \
    const int srow = tid >> 2;                                               \
    const int sch  = tid & 3;                                                \
    const int sc0  = (sch ^ ((srow >> 1) & 3)) * 8;

// ---------------------------------------------------------------------------
// FFN pass 1 (production, global dynamic ticket)
// ---------------------------------------------------------------------------
__global__ __launch_bounds__(512, 1) void ffn1_kernel(
    const __hip_bfloat16* __restrict__ xb, const __hip_bfloat16* __restrict__ w1t,
    const float* __restrict__ b1, const int* __restrict__ counts,
    const int* __restrict__ base, const int* __restrict__ tlist,
    const int* __restrict__ task1, const int* __restrict__ ntasks,
    int* __restrict__ ticket, __hip_bfloat16* __restrict__ H)
{
    __shared__ __align__(16) ushort lds[65536];   // 128 KiB
    __shared__ int s_task;
    CORE_IDX
    const int nt1 = ntasks[0];

    for (;;) {
        __syncthreads();
        if (tid == 0) s_task = atomicAdd(ticket, 1);
        __syncthreads();
        const int task = s_task;
        if (task >= nt1) break;
        const int v  = task1[task];
        const int e  = v >> 16, rb = (v >> 8) & 255, cb = v & 255;
        const int ne = counts[e];
        const int hb = base[e];

        const int rA0g = rb * 256 + srow;
        const int rA1g = rA0g + 128;
        const int tok0 = tlist[e * CAP + (rA0g < ne ? rA0g : ne - 1)];
        const int tok1 = tlist[e * CAP + (rA1g < ne ? rA1g : ne - 1)];
        const ushort* srcA0 = (const ushort*)xb + (size_t)tok0 * DIM + sc0;
        const ushort* srcA1 = (const ushort*)xb + (size_t)tok1 * DIM + sc0;
        const ushort* srcB0 = (const ushort*)w1t + ((size_t)e * HID + cb * 256 + srow) * DIM + sc0;
        const ushort* srcB1 = srcB0 + (size_t)128 * DIM;

        GEMM_CORE(16, srcA0, srcA1, srcB0, srcB1)

#pragma unroll
        for (int nj = 0; nj < 4; nj++) {
            int col = cb * 256 + wc * 64 + nj * 16 + lm;
            float bias = b1[e * HID + col];
#pragma unroll
            for (int mi = 0; mi < 8; mi++) {
#pragma unroll
                for (int jj = 0; jj < 4; jj++) {
                    int r = rb * 256 + wr * 128 + mi * 16 + kg * 4 + jj;
                    if (r < ne) {
                        float vv = acc[mi][nj][jj] + bias;
                        vv = 0.5f * vv * (1.0f + erff(vv * 0.70710678118654752f));
                        H[(size_t)(hb + r) * HID + col] = __float2bfloat16(vv);
                    }
                }
            }
        }
    }
}

// ---------------------------------------------------------------------------
// FFN pass 2 (production, global dynamic ticket, split-K=4)
// ---------------------------------------------------------------------------
__global__ __launch_bounds__(512, 1) void ffn2_kernel(
    const __hip_bfloat16* __restrict__ H, const __hip_bfloat16* __restrict__ w2t,
    const float* __restrict__ b2, const int* __restrict__ counts,
    const int* __restrict__ base, const int* __restrict__ tlist,
    const float* __restrict__ plist, const int* __restrict__ task2,
    const int* __restrict__ ntasks, int* __restrict__ ticket,
    float* __restrict__ out)
{
    __shared__ __align__(16) ushort lds[65536];   // 128 KiB
    __shared__ int s_task;
    CORE_IDX
    const int nt2 = ntasks[1];

    for (;;) {
        __syncthreads();
        if (tid == 0) s_task = atomicAdd(ticket, 1);
        __syncthreads();
        const int task = s_task;
        if (task >= nt2) break;
        const int v  = task2[task];
        const int e  = v >> 16, rb = (v >> 8) & 255;
        const int c  = v & 255;
        const int cb = c >> 2, sp = c & 3;
        const int ne = counts[e];
        const int hb = base[e];

        const int rA0g = rb * 256 + srow;
        const int rA1g = rA0g + 128;
        const int hr0  = hb + (rA0g < ne ? rA0g : ne - 1);
        const int hr1  = hb + (rA1g < ne ? rA1g : ne - 1);
        const size_t ko0 = (size_t)sp * KSP;
        const ushort* srcA0 = (const ushort*)H + (size_t)hr0 * HID + ko0 + sc0;
        const ushort* srcA1 = (const ushort*)H + (size_t)hr1 * HID + ko0 + sc0;
        const ushort* srcB0 = (const ushort*)w2t + ((size_t)e * DIM + cb * 256 + srow) * HID + ko0 + sc0;
        const ushort* srcB1 = srcB0 + (size_t)128 * HID;

        GEMM_CORE(16, srcA0, srcA1, srcB0, srcB1)

#pragma unroll
        for (int mi = 0; mi < 8; mi++) {
#pragma unroll
            for (int jj = 0; jj < 4; jj++) {
                int r = rb * 256 + wr * 128 + mi * 16 + kg * 4 + jj;
                if (r < ne) {
                    int tok = tlist[e * CAP + r];
                    float p = plist[e * CAP + r];
                    float* orow = out + (size_t)tok * DIM;
#pragma unroll
                    for (int nj = 0; nj < 4; nj++) {
                        int col = cb * 256 + wc * 64 + nj * 16 + lm;
                        float vv = acc[mi][nj][jj];
                        if (sp == 0) vv += b2[e * DIM + col];
                        unsafeAtomicAdd(&orow[col], vv * p);
                    }
                }
            }
        }
    }
}

// ===========================================================================
// DIAGNOSTIC kernels (write only to dead scratch; acc kept live via sink).
// Sized LARGER than production so they appear in the top-5 dispatch table.
// per_tile_cycles = dur_us * 2400 / tiles_per_CU.
// ===========================================================================

// dbg1: real staging sources, NO epilogue. 8 tasks x 16 K-tiles = 128/CU.
__global__ __launch_bounds__(512, 1) void dbg1_realsrc_noepi(
    const __hip_bfloat16* __restrict__ H, const __hip_bfloat16* __restrict__ w2t,
    const int* __restrict__ counts, const int* __restrict__ base,
    float* __restrict__ sink)
{
    __shared__ __align__(16) ushort lds[65536];
    CORE_IDX
    const int b  = blockIdx.x;
    const int e  = b & 7;
    const int ne = counts[e];
    const int hb = base[e];
    float s_acc = 0.f;

    for (int r = 0; r < 8; r++) {
        const int rb = (b >> 3) & 3;
        const int c  = (b + r) & 15;
        const int cb = c >> 2, sp = c & 3;
        __syncthreads();
        const int rA0g = rb * 256 + srow;
        const int rA1g = rA0g + 128;
        const int hr0  = hb + (rA0g < ne ? rA0g : ne - 1);
        const int hr1  = hb + (rA1g < ne ? rA1g : ne - 1);
        const size_t ko0 = (size_t)sp * KSP;
        const ushort* srcA0 = (const ushort*)H + (size_t)hr0 * HID + ko0 + sc0;
        const ushort* srcA1 = (const ushort*)H + (size_t)hr1 * HID + ko0 + sc0;
        const ushort* srcB0 = (const ushort*)w2t + ((size_t)e * DIM + cb * 256 + srow) * HID + ko0 + sc0;
        const ushort* srcB1 = srcB0 + (size_t)128 * HID;

        GEMM_CORE_V(16, srcA0, srcA1, srcB0, srcB1, 1, 1)

#pragma unroll
        for (int mi = 0; mi < 8; mi++)
#pragma unroll
            for (int nj = 0; nj < 4; nj++)
                s_acc += acc[mi][nj][0] + acc[mi][nj][1] + acc[mi][nj][2] + acc[mi][nj][3];
    }
    sink[(size_t)b * 512 + tid] = s_acc;
}

// dbg2: L2/L1-resident staging (KMUL=0 -> same 32KB re-read), NO epilogue.
// 12 tasks x 16 = 192 K-tiles/CU.
__global__ __launch_bounds__(512, 1) void dbg2_l2res_noepi(
    const __hip_bfloat16* __restrict__ H, const __hip_bfloat16* __restrict__ w2t,
    const int* __restrict__ counts, const int* __restrict__ base,
    float* __restrict__ sink)
{
    __shared__ __align__(16) ushort lds[65536];
    CORE_IDX
    const int b  = blockIdx.x;
    const int e  = b & 7;
    const int ne = counts[e];
    const int hb = base[e];
    float s_acc = 0.f;

    for (int r = 0; r < 12; r++) {
        __syncthreads();
        const int rA0g = srow;
        const int hr0  = hb + (rA0g < ne ? rA0g : ne - 1);
        const ushort* srcA0 = (const ushort*)H + (size_t)hr0 * HID + sc0;
        const ushort* srcA1 = srcA0;
        const ushort* srcB0 = (const ushort*)w2t + ((size_t)e * DIM + srow) * HID + sc0;
        const ushort* srcB1 = srcB0;

        GEMM_CORE_V(16, srcA0, srcA1, srcB0, srcB1, 0, 1)

#pragma unroll
        for (int mi = 0; mi < 8; mi++)
#pragma unroll
            for (int nj = 0; nj < 4; nj++)
                s_acc += acc[mi][nj][0] + acc[mi][nj][1] + acc[mi][nj][2] + acc[mi][nj][3];
    }
    sink[(size_t)b * 512 + tid] = s_acc;
}

// dbg3: NO staging at all (skeleton: barriers + ds_read + MFMA).
// 16 tasks x 16 = 256 K-tiles/CU.
__global__ __launch_bounds__(512, 1) void dbg3_noload(
    const __hip_bfloat16* __restrict__ H, const __hip_bfloat16* __restrict__ w2t,
    float* __restrict__ sink)
{
    __shared__ __align__(16) ushort lds[65536];
    CORE_IDX
    const int b = blockIdx.x;
    float s_acc = 0.f;

    for (int r = 0; r < 16; r++) {
        __syncthreads();
        const ushort* srcA0 = (const ushort*)H;
        const ushort* srcA1 = srcA0;
        const ushort* srcB0 = (const ushort*)w2t;
        const ushort* srcB1 = srcB0;

        GEMM_CORE_V(16, srcA0, srcA1, srcB0, srcB1, 0, 0)

#pragma unroll
        for (int mi = 0; mi < 8; mi++)
#pragma unroll
            for (int nj = 0; nj < 4; nj++)
                s_acc += acc[mi][nj][0] + acc[mi][nj][1] + acc[mi][nj][2] + acc[mi][nj][3];
    }
    sink[(size_t)b * 512 + tid] = s_acc;
}

// ---------------------------------------------------------------------------
extern "C" void kernel_launch(void* const* d_in, const int* in_sizes, int n_in,
                              void* d_out, int out_size, void* d_ws, size_t ws_size,
                              hipStream_t stream)
{
    const float* x  = (const float*)d_in[0];
    const float* gw = (const float*)d_in[1];
    const float* gb = (const float*)d_in[2];
    const float* w1 = (const float*)d_in[3];
    const float* b1 = (const float*)d_in[4];
    const float* w2 = (const float*)d_in[5];
    const float* b2 = (const float*)d_in[6];
    float* out = (float*)d_out;

    // workspace carve (bytes)
    char* ws = (char*)d_ws;
    __hip_bfloat16* w1t = (__hip_bfloat16*)(ws);                    // 67108864
    __hip_bfloat16* w2t = (__hip_bfloat16*)(ws + 67108864);         // 67108864
    __hip_bfloat16* Hb  = (__hip_bfloat16*)(ws + 134217728);        // 67108864
    __hip_bfloat16* xb  = (__hip_bfloat16*)(ws + 201326592);        // 8388608
    int*   tlist  = (int*)  (ws + 209715200);                       // 131072
    float* plist  = (float*)(ws + 209846272);                       // 131072
    int*   counts = (int*)  (ws + 209977344);                       // 64
    int*   basep  = (int*)  (ws + 209977408);                       // 64
    int*   ntasks = (int*)  (ws + 209977472);                       // 64
    int*   tickets= (int*)  (ws + 209977536);                       // 64
    int*   task1  = (int*)  (ws + 209977600);                       // 8192
    int*   task2  = (int*)  (ws + 209985792);                       // 8192
    float* dbgsink= (float*)(ws);   // reuse w1t area: dead after ffn1

    hipMemsetAsync(out, 0, (size_t)T_TOKENS * DIM * sizeof(float), stream);
    hipMemsetAsync(counts, 0, 256, stream);   // counts+basep+ntasks+tickets

    gate_kernel<<<T_TOKENS, 64, 0, stream>>>(x, gw, gb, xb, counts, tlist, plist);
    finalize_kernel<<<1, 64, 0, stream>>>(counts, basep, task1, task2, ntasks);

    transpose_cvt64<<<dim3(HID / 64, DIM / 64, NE), 256, 0, stream>>>(w1, w1t, DIM, HID);
    transpose_cvt64<<<dim3(DIM / 64, HID / 64, NE), 256, 0, stream>>>(w2, w2t, HID, DIM);

    // production (unchanged from R9)
    ffn1_kernel<<<256, 512, 0, stream>>>(
        xb, w1t, b1, counts, basep, tlist, task1, ntasks, &tickets[0], Hb);
    ffn2_kernel<<<256, 512, 0, stream>>>(
        Hb, w2t, b2, counts, basep, tlist, plist, task2, ntasks, &tickets[1], out);

    // diagnostics (after production; write only to dead w1t scratch)
    dbg1_realsrc_noepi<<<256, 512, 0, stream>>>(Hb, w2t, counts, basep, dbgsink);
    dbg2_l2res_noepi <<<256, 512, 0, stream>>>(Hb, w2t, counts, basep, dbgsink + (1 << 17));
    dbg3_noload      <<<256, 512, 0, stream>>>(Hb, w2t, dbgsink + (2 << 17));
}

// Round 11
// 496.100 us; speedup vs baseline: 2.6709x; 2.6709x over previous
//
#include <hip/hip_runtime.h>
#include <hip/hip_bf16.h>

// Problem constants
#define T_TOKENS 4096      // B*S
#define DIM      1024
#define HID      4096
#define NE       8
#define CAP      4096      // max tokens per expert
#define SPLITS   4         // split-K factor for ffn2
#define KSP      (HID / SPLITS)   // 1024

typedef __attribute__((ext_vector_type(8))) short  bf16x8;
typedef __attribute__((ext_vector_type(4))) float  f32x4;
typedef __attribute__((ext_vector_type(4))) ushort u16x4;

__device__ static inline ushort f2bf(float f) {
    __hip_bfloat16 h = __float2bfloat16(f);
    return *(ushort*)&h;
}

// async global -> LDS, 16 bytes per lane. LDS dest = wave-uniform base +
// lane*16 (linear). Swizzle applied on the GLOBAL source address.
__device__ static inline void gll16(const void* g, void* l) {
    __builtin_amdgcn_global_load_lds(
        (const __attribute__((address_space(1))) void*)g,
        (__attribute__((address_space(3))) void*)l,
        16, 0, 0);
}

#define MFMA16(a, b, c) __builtin_amdgcn_mfma_f32_16x16x32_bf16((a), (b), (c), 0, 0, 0)

// ---------------------------------------------------------------------------
// Gate: logits -> top2 -> softmax -> per-expert token lists; also x -> bf16.
// tlist entry packs: tok (bits 0-11) | expert-slot k (bit 15; 0 = token's
// top-1 expert, 1 = top-2) — consumed by ffn2's slot-buffer epilogue.
// ---------------------------------------------------------------------------
__global__ __launch_bounds__(64) void gate_kernel(
    const float* __restrict__ x, const float* __restrict__ gw,
    const float* __restrict__ gb, __hip_bfloat16* __restrict__ xb,
    int* __restrict__ counts, int* __restrict__ tlist, float* __restrict__ plist)
{
    const int tok = blockIdx.x;
    const int l   = threadIdx.x;
    const float* xr = x + (size_t)tok * DIM;

    float part[NE];
#pragma unroll
    for (int e = 0; e < NE; e++) part[e] = 0.f;

#pragma unroll
    for (int i = 0; i < DIM / 64; i++) {
        int d = i * 64 + l;
        float xv = xr[d];
        xb[(size_t)tok * DIM + d] = __float2bfloat16(xv);
        const float4* g4 = (const float4*)(gw + (size_t)d * NE);
        float4 a = g4[0], b = g4[1];
        part[0] += xv * a.x; part[1] += xv * a.y;
        part[2] += xv * a.z; part[3] += xv * a.w;
        part[4] += xv * b.x; part[5] += xv * b.y;
        part[6] += xv * b.z; part[7] += xv * b.w;
    }
#pragma unroll
    for (int off = 32; off > 0; off >>= 1) {
#pragma unroll
        for (int e = 0; e < NE; e++) part[e] += __shfl_xor(part[e], off, 64);
    }
    if (l == 0) {
        float lg[NE];
#pragma unroll
        for (int e = 0; e < NE; e++) lg[e] = part[e] + gb[e];
        int i0 = 0;
#pragma unroll
        for (int e = 1; e < NE; e++) if (lg[e] > lg[i0]) i0 = e;   // lowest idx on tie
        int i1 = (i0 == 0) ? 1 : 0;
#pragma unroll
        for (int e = 0; e < NE; e++) if (e != i0 && lg[e] > lg[i1]) i1 = e;
        float t  = expf(lg[i1] - lg[i0]);
        float p0 = 1.f / (1.f + t);
        float p1 = t / (1.f + t);
        int pos0 = atomicAdd(&counts[i0], 1);
        tlist[i0 * CAP + pos0] = tok;              plist[i0 * CAP + pos0] = p0;
        int pos1 = atomicAdd(&counts[i1], 1);
        tlist[i1 * CAP + pos1] = tok | (1 << 15);  plist[i1 * CAP + pos1] = p1;
    }
}

// ---------------------------------------------------------------------------
// finalize: prefix-sum bases + build global task lists (expert-major,
// rb-major inner).
// ---------------------------------------------------------------------------
__global__ void finalize_kernel(const int* __restrict__ counts, int* __restrict__ base,
                                int* __restrict__ task1, int* __restrict__ task2,
                                int* __restrict__ ntasks)
{
    __shared__ int stc[NE], so1[NE], so2[NE];
    if (threadIdx.x == 0) {
        int acc = 0, o1 = 0, o2 = 0;
        for (int e = 0; e < NE; e++) {
            base[e] = acc; acc += counts[e];
            int tc = (counts[e] + 255) >> 8;
            stc[e] = tc; so1[e] = o1; so2[e] = o2;
            o1 += tc * 16; o2 += tc * 16;
        }
        base[NE] = acc;
        ntasks[0] = o1; ntasks[1] = o2;
    }
    __syncthreads();
    for (int e = 0; e < NE; e++) {
        int tc = stc[e];
        for (int i = threadIdx.x; i < tc * 16; i += 64) {
            int rb = i >> 4, cb = i & 15;
            task1[so1[e] + i] = (e << 16) | (rb << 8) | cb;
        }
        for (int i = threadIdx.x; i < tc * 16; i += 64) {
            int rb = i >> 4, c = i & 15;      // c = cb*4+sp
            task2[so2[e] + i] = (e << 16) | (rb << 8) | c;
        }
    }
}

// ---------------------------------------------------------------------------
// Transpose + f32->bf16 convert:  in [E][K][N] f32  ->  out [E][N][K] bf16
// ---------------------------------------------------------------------------
__global__ __launch_bounds__(256) void transpose_cvt64(
    const float* __restrict__ in, __hip_bfloat16* __restrict__ outp, int K, int N)
{
    __shared__ ushort tile[64][68];
    const int e  = blockIdx.z;
    const float* src = in + (size_t)e * K * N;
    ushort* dst = (ushort*)outp + (size_t)e * K * N;
    const int k0 = blockIdx.y * 64, n0 = blockIdx.x * 64;
    const int tid = threadIdx.x;

    const int rn4 = (tid & 15) * 4;
    const int rk  = tid >> 4;
#pragma unroll
    for (int p = 0; p < 4; p++) {
        int k = rk + p * 16;
        float4 v = *(const float4*)&src[(size_t)(k0 + k) * N + n0 + rn4];
        tile[k][rn4 + 0] = f2bf(v.x);
        tile[k][rn4 + 1] = f2bf(v.y);
        tile[k][rn4 + 2] = f2bf(v.z);
        tile[k][rn4 + 3] = f2bf(v.w);
    }
    __syncthreads();
    const int wk4 = (tid & 15) * 4;
    const int wn  = tid >> 4;
#pragma unroll
    for (int p = 0; p < 4; p++) {
        int n = wn + p * 16;
        u16x4 u;
        u[0] = tile[wk4 + 0][n];
        u[1] = tile[wk4 + 1][n];
        u[2] = tile[wk4 + 2][n];
        u[3] = tile[wk4 + 3][n];
        *(u16x4*)&dst[(size_t)(n0 + n) * K + k0 + wk4] = u;
    }
}

// ===========================================================================
// 256x256 8-phase grouped GEMM core (BM=BN=256, BK=64, 8 waves 2Mx4N).
// R10 ablation: skeleton <=3.3K cy/tile, +L2-staging 4.46K @ 52% MfmaUtil,
// +real-mem <=6.6K. The core is NOT the production bottleneck; epilogue was.
// ===========================================================================

#define AOFFc(d,s) (((d)*2+(s))*8192)
#define BOFFc(d,s) (32768 + ((d)*2+(s))*8192)

#define MFMA_CL(nj0, nj1)                                                    \
    _Pragma("unroll")                                                        \
    for (int mi = 0; mi < 8; mi++) {                                         \
        acc[mi][nj0] = MFMA16(af[mi], bf##nj0, acc[mi][nj0]);                \
        acc[mi][nj1] = MFMA16(af[mi], bf##nj1, acc[mi][nj1]);                \
    }

#define GEMM_CORE(NT, srcA0, srcA1, srcB0, srcB1)                            \
    f32x4 acc[8][4];                                                         \
    _Pragma("unroll")                                                        \
    for (int i = 0; i < 8; i++)                                              \
        _Pragma("unroll")                                                    \
        for (int j = 0; j < 4; j++) acc[i][j] = (f32x4){0.f,0.f,0.f,0.f};    \
    const int a0 = (wr * 128 + lm) * 32 + rch;                               \
    const int b0 = (wc * 64 + lm) * 32 + rch;                                \
    gll16(srcA0,      &lds[AOFFc(0,0) + w*512]);                             \
    gll16(srcA1,      &lds[AOFFc(0,0) + 4096 + w*512]);                      \
    gll16(srcB0,      &lds[BOFFc(0,0) + w*512]);                             \
    gll16(srcB1,      &lds[BOFFc(0,0) + 4096 + w*512]);                      \
    gll16(srcA0 + 32, &lds[AOFFc(0,1) + w*512]);                             \
    gll16(srcA1 + 32, &lds[AOFFc(0,1) + 4096 + w*512]);                      \
    gll16(srcB0 + 32, &lds[BOFFc(0,1) + w*512]);                             \
    gll16(srcB1 + 32, &lds[BOFFc(0,1) + 4096 + w*512]);                      \
    asm volatile("s_waitcnt vmcnt(4)" ::: "memory");                         \
    gll16(srcA0 + 64, &lds[AOFFc(1,0) + w*512]);                             \
    gll16(srcA1 + 64, &lds[AOFFc(1,0) + 4096 + w*512]);                      \
    gll16(srcB0 + 64, &lds[BOFFc(1,0) + w*512]);                             \
    gll16(srcB1 + 64, &lds[BOFFc(1,0) + 4096 + w*512]);                      \
    gll16(srcA0 + 96, &lds[AOFFc(1,1) + w*512]);                             \
    gll16(srcA1 + 96, &lds[AOFFc(1,1) + 4096 + w*512]);                      \
    asm volatile("s_waitcnt vmcnt(6)" ::: "memory");                         \
    __builtin_amdgcn_s_barrier();                                            \
    _Pragma("unroll 1")                                                      \
    for (int t = 0; t < NT; t++) {                                           \
        const int d   = t & 1;                                               \
        const int aof  = d * 16384,        bof  = 32768 + d * 16384;         \
        const int bofN = 32768 + (d^1) * 16384;                              \
        bf16x8 af[8]; bf16x8 bf0, bf1, bf2, bf3;                             \
        _Pragma("unroll")                                                    \
        for (int mi = 0; mi < 8; mi++)                                       \
            af[mi] = *(const bf16x8*)&lds[aof + a0 + mi*512];                \
        bf0 = *(const bf16x8*)&lds[bof + b0];                                \
        bf1 = *(const bf16x8*)&lds[bof + b0 + 512];                          \
        if (t + 1 < NT) {                                                    \
            size_t ko = (size_t)(t+1)*64 + 32;                               \
            gll16(srcB0 + ko, &lds[bofN + 8192 + w*512]);                    \
            gll16(srcB1 + ko, &lds[bofN + 8192 + 4096 + w*512]);             \
        }                                                                    \
        __builtin_amdgcn_s_barrier();                                        \
        __builtin_amdgcn_s_setprio(1);                                       \
        MFMA_CL(0, 1)                                                        \
        __builtin_amdgcn_s_setprio(0);                                       \
        __builtin_amdgcn_s_barrier();                                        \
        bf2 = *(const bf16x8*)&lds[bof + b0 + 1024];                         \
        bf3 = *(const bf16x8*)&lds[bof + b0 + 1536];                         \
        if (t + 2 < NT) {                                                    \
            size_t ko = (size_t)(t+2)*64;                                    \
            gll16(srcA0 + ko, &lds[aof + w*512]);                            \
            gll16(srcA1 + ko, &lds[aof + 4096 + w*512]);                     \
        }                                                                    \
        __builtin_amdgcn_s_barrier();                                        \
        __builtin_amdgcn_s_setprio(1);                                       \
        MFMA_CL(2, 3)                                                        \
        __builtin_amdgcn_s_setprio(0);                                       \
        __builtin_amdgcn_s_barrier();                                        \
        _Pragma("unroll")                                                    \
        for (int mi = 0; mi < 8; mi++)                                       \
            af[mi] = *(const bf16x8*)&lds[aof + 8192 + a0 + mi*512];         \
        bf0 = *(const bf16x8*)&lds[bof + 8192 + b0];                         \
        bf1 = *(const bf16x8*)&lds[bof + 8192 + b0 + 512];                   \
        if (t + 2 < NT) {                                                    \
            size_t ko = (size_t)(t+2)*64;                                    \
            gll16(srcB0 + ko, &lds[bof + w*512]);                            \
            gll16(srcB1 + ko, &lds[bof + 4096 + w*512]);                     \
        }                                                                    \
        __builtin_amdgcn_s_barrier();                                        \
        __builtin_amdgcn_s_setprio(1);                                       \
        MFMA_CL(0, 1)                                                        \
        __builtin_amdgcn_s_setprio(0);                                       \
        __builtin_amdgcn_s_barrier();                                        \
        bf2 = *(const bf16x8*)&lds[bof + 8192 + b0 + 1024];                  \
        bf3 = *(const bf16x8*)&lds[bof + 8192 + b0 + 1536];                  \
        if (t + 2 < NT) {                                                    \
            size_t ko = (size_t)(t+2)*64 + 32;                               \
            gll16(srcA0 + ko, &lds[aof + 8192 + w*512]);                     \
            gll16(srcA1 + ko, &lds[aof + 8192 + 4096 + w*512]);              \
        }                                                                    \
        __builtin_amdgcn_s_barrier();                                        \
        __builtin_amdgcn_s_setprio(1);                                       \
        MFMA_CL(2, 3)                                                        \
        __builtin_amdgcn_s_setprio(0);                                       \
        if (t < NT - 2) { asm volatile("s_waitcnt vmcnt(6)" ::: "memory"); } \
        else            { asm volatile("s_waitcnt vmcnt(0)" ::: "memory"); } \
        __builtin_amdgcn_s_barrier();                                        \
    }

// Common per-thread index setup
#define CORE_IDX                                                             \
    const int tid = threadIdx.x;                                             \
    const int l = tid & 63, w = tid >> 6;                                    \
    const int wr = w >> 2, wc = w & 3;                                       \
    const int lm = l & 15, kg = l >> 4;                                      \
    const int rch = (kg ^ ((lm >> 1) & 3)) * 8;                              \
    const int srow = tid >> 2;                                               \
    const int sch  = tid & 3;                                                \
    const int sc0  = (sch ^ ((srow >> 1) & 3)) * 8;

// ---------------------------------------------------------------------------
// FFN pass 1 (global dynamic ticket):  H = gelu( gather(xb) @ w1t^T + b1 )
// ---------------------------------------------------------------------------
__global__ __launch_bounds__(512, 1) void ffn1_kernel(
    const __hip_bfloat16* __restrict__ xb, const __hip_bfloat16* __restrict__ w1t,
    const float* __restrict__ b1, const int* __restrict__ counts,
    const int* __restrict__ base, const int* __restrict__ tlist,
    const int* __restrict__ task1, const int* __restrict__ ntasks,
    int* __restrict__ ticket, __hip_bfloat16* __restrict__ H)
{
    __shared__ __align__(16) ushort lds[65536];   // 128 KiB
    __shared__ int s_task;
    CORE_IDX
    const int nt1 = ntasks[0];

    for (;;) {
        __syncthreads();
        if (tid == 0) s_task = atomicAdd(ticket, 1);
        __syncthreads();
        const int task = s_task;
        if (task >= nt1) break;
        const int v  = task1[task];
        const int e  = v >> 16, rb = (v >> 8) & 255, cb = v & 255;
        const int ne = counts[e];
        const int hb = base[e];

        const int rA0g = rb * 256 + srow;
        const int rA1g = rA0g + 128;
        const int tok0 = tlist[e * CAP + (rA0g < ne ? rA0g : ne - 1)] & 0xFFF;
        const int tok1 = tlist[e * CAP + (rA1g < ne ? rA1g : ne - 1)] & 0xFFF;
        const ushort* srcA0 = (const ushort*)xb + (size_t)tok0 * DIM + sc0;
        const ushort* srcA1 = (const ushort*)xb + (size_t)tok1 * DIM + sc0;
        const ushort* srcB0 = (const ushort*)w1t + ((size_t)e * HID + cb * 256 + srow) * DIM + sc0;
        const ushort* srcB1 = srcB0 + (size_t)128 * DIM;

        GEMM_CORE(16, srcA0, srcA1, srcB0, srcB1)

#pragma unroll
        for (int nj = 0; nj < 4; nj++) {
            int col = cb * 256 + wc * 64 + nj * 16 + lm;
            float bias = b1[e * HID + col];
#pragma unroll
            for (int mi = 0; mi < 8; mi++) {
#pragma unroll
                for (int jj = 0; jj < 4; jj++) {
                    int r = rb * 256 + wr * 128 + mi * 16 + kg * 4 + jj;
                    if (r < ne) {
                        float vv = acc[mi][nj][jj] + bias;
                        vv = 0.5f * vv * (1.0f + erff(vv * 0.70710678118654752f));
                        H[(size_t)(hb + r) * HID + col] = __float2bfloat16(vv);
                    }
                }
            }
        }
    }
}

// ---------------------------------------------------------------------------
// FFN pass 2 (global dynamic ticket, split-K=4, NO ATOMICS):
// each (expert-slot k, split sp) contribution goes to its own slot of
// Y[8][T][D] (bf16, plain stores; every element written exactly once).
// slot = k*4+sp; bias folded into sp==0; p multiplied per slot.
// ---------------------------------------------------------------------------
__global__ __launch_bounds__(512, 1) void ffn2_kernel(
    const __hip_bfloat16* __restrict__ H, const __hip_bfloat16* __restrict__ w2t,
    const float* __restrict__ b2, const int* __restrict__ counts,
    const int* __restrict__ base, const int* __restrict__ tlist,
    const float* __restrict__ plist, const int* __restrict__ task2,
    const int* __restrict__ ntasks, int* __restrict__ ticket,
    __hip_bfloat16* __restrict__ Y)
{
    __shared__ __align__(16) ushort lds[65536];   // 128 KiB
    __shared__ int s_task;
    CORE_IDX
    const int nt2 = ntasks[1];

    for (;;) {
        __syncthreads();
        if (tid == 0) s_task = atomicAdd(ticket, 1);
        __syncthreads();
        const int task = s_task;
        if (task >= nt2) break;
        const int v  = task2[task];
        const int e  = v >> 16, rb = (v >> 8) & 255;
        const int c  = v & 255;
        const int cb = c >> 2, sp = c & 3;
        const int ne = counts[e];
        const int hb = base[e];

        const int rA0g = rb * 256 + srow;
        const int rA1g = rA0g + 128;
        const int hr0  = hb + (rA0g < ne ? rA0g : ne - 1);
        const int hr1  = hb + (rA1g < ne ? rA1g : ne - 1);
        const size_t ko0 = (size_t)sp * KSP;
        const ushort* srcA0 = (const ushort*)H + (size_t)hr0 * HID + ko0 + sc0;
        const ushort* srcA1 = (const ushort*)H + (size_t)hr1 * HID + ko0 + sc0;
        const ushort* srcB0 = (const ushort*)w2t + ((size_t)e * DIM + cb * 256 + srow) * HID + ko0 + sc0;
        const ushort* srcB1 = srcB0 + (size_t)128 * HID;

        GEMM_CORE(16, srcA0, srcA1, srcB0, srcB1)

        // epilogue: plain bf16 stores into per-slot buffer (no atomics)
#pragma unroll
        for (int mi = 0; mi < 8; mi++) {
#pragma unroll
            for (int jj = 0; jj < 4; jj++) {
                int r = rb * 256 + wr * 128 + mi * 16 + kg * 4 + jj;
                if (r < ne) {
                    int tv  = tlist[e * CAP + r];
                    int tok = tv & 0xFFF;
                    int kk  = tv >> 15;
                    float p = plist[e * CAP + r];
                    __hip_bfloat16* yrow =
                        Y + ((size_t)(kk * 4 + sp) * T_TOKENS + tok) * DIM;
#pragma unroll
                    for (int nj = 0; nj < 4; nj++) {
                        int col = cb * 256 + wc * 64 + nj * 16 + lm;
                        float vv = acc[mi][nj][jj];
                        if (sp == 0) vv += b2[e * DIM + col];
                        yrow[col] = __float2bfloat16(vv * p);
                    }
                }
            }
        }
    }
}

// ---------------------------------------------------------------------------
// Reduce: out[t][d] = sum of 8 slots (fixed order -> bitwise deterministic).
// ---------------------------------------------------------------------------
__global__ __launch_bounds__(256) void reduce_kernel(
    const __hip_bfloat16* __restrict__ Y, float* __restrict__ out)
{
    const size_t i = ((size_t)blockIdx.x * 256 + threadIdx.x) * 8;
    float s[8];
#pragma unroll
    for (int j = 0; j < 8; j++) s[j] = 0.f;
#pragma unroll
    for (int sl = 0; sl < 8; sl++) {
        bf16x8 v = *(const bf16x8*)((const ushort*)Y + (size_t)sl * T_TOKENS * DIM + i);
#pragma unroll
        for (int j = 0; j < 8; j++) {
            union { unsigned int ui; float f; } cv;
            cv.ui = ((unsigned int)(ushort)v[j]) << 16;
            s[j] += cv.f;
        }
    }
#pragma unroll
    for (int j = 0; j < 8; j++) out[i + j] = s[j];
}

// ---------------------------------------------------------------------------
extern "C" void kernel_launch(void* const* d_in, const int* in_sizes, int n_in,
                              void* d_out, int out_size, void* d_ws, size_t ws_size,
                              hipStream_t stream)
{
    const float* x  = (const float*)d_in[0];
    const float* gw = (const float*)d_in[1];
    const float* gb = (const float*)d_in[2];
    const float* w1 = (const float*)d_in[3];
    const float* b1 = (const float*)d_in[4];
    const float* w2 = (const float*)d_in[5];
    const float* b2 = (const float*)d_in[6];
    float* out = (float*)d_out;

    // workspace carve (bytes)
    char* ws = (char*)d_ws;
    __hip_bfloat16* w1t = (__hip_bfloat16*)(ws);                    // 67108864
    __hip_bfloat16* w2t = (__hip_bfloat16*)(ws + 67108864);         // 67108864
    __hip_bfloat16* Hb  = (__hip_bfloat16*)(ws + 134217728);        // 67108864
    __hip_bfloat16* xb  = (__hip_bfloat16*)(ws + 201326592);        // 8388608
    int*   tlist  = (int*)  (ws + 209715200);                       // 131072
    float* plist  = (float*)(ws + 209846272);                       // 131072
    int*   counts = (int*)  (ws + 209977344);                       // 64
    int*   basep  = (int*)  (ws + 209977408);                       // 64
    int*   ntasks = (int*)  (ws + 209977472);                       // 64
    int*   tickets= (int*)  (ws + 209977536);                       // 64
    int*   task1  = (int*)  (ws + 209977600);                       // 8192
    int*   task2  = (int*)  (ws + 209985792);                       // 8192
    // Y slot buffer reuses w1t's 64 MB: w1t is dead once ffn1 completes
    // (stream-ordered), and Y = 8 slots x 4096 tok x 1024 x bf16 = 64 MB.
    __hip_bfloat16* Y = (__hip_bfloat16*)(ws);

    hipMemsetAsync(counts, 0, 256, stream);   // counts+basep+ntasks+tickets

    gate_kernel<<<T_TOKENS, 64, 0, stream>>>(x, gw, gb, xb, counts, tlist, plist);
    finalize_kernel<<<1, 64, 0, stream>>>(counts, basep, task1, task2, ntasks);

    transpose_cvt64<<<dim3(HID / 64, DIM / 64, NE), 256, 0, stream>>>(w1, w1t, DIM, HID);
    transpose_cvt64<<<dim3(DIM / 64, HID / 64, NE), 256, 0, stream>>>(w2, w2t, HID, DIM);

    ffn1_kernel<<<256, 512, 0, stream>>>(
        xb, w1t, b1, counts, basep, tlist, task1, ntasks, &tickets[0], Hb);
    ffn2_kernel<<<256, 512, 0, stream>>>(
        Hb, w2t, b2, counts, basep, tlist, plist, task2, ntasks, &tickets[1], Y);
    reduce_kernel<<<(T_TOKENS * DIM / 8) / 256, 256, 0, stream>>>(Y, out);
}

// Round 12
// 462.229 us; speedup vs baseline: 2.8666x; 1.0733x over previous
//
#include <hip/hip_runtime.h>
#include <hip/hip_bf16.h>

// Problem constants
#define T_TOKENS 4096      // B*S
#define DIM      1024
#define HID      4096
#define NE       8
#define CAP      4096      // max tokens per expert
#define SPLITS   4         // split-K factor for ffn2
#define KSP      (HID / SPLITS)   // 1024

typedef __attribute__((ext_vector_type(8))) short  bf16x8;
typedef __attribute__((ext_vector_type(4))) float  f32x4;
typedef __attribute__((ext_vector_type(4))) ushort u16x4;

__device__ static inline ushort f2bf(float f) {
    __hip_bfloat16 h = __float2bfloat16(f);
    return *(ushort*)&h;
}

// async global -> LDS, 16 bytes per lane. LDS dest = wave-uniform base +
// lane*16 (linear). Swizzle applied on the GLOBAL source address.
__device__ static inline void gll16(const void* g, void* l) {
    __builtin_amdgcn_global_load_lds(
        (const __attribute__((address_space(1))) void*)g,
        (__attribute__((address_space(3))) void*)l,
        16, 0, 0);
}

#define MFMA16(a, b, c) __builtin_amdgcn_mfma_f32_16x16x32_bf16((a), (b), (c), 0, 0, 0)

// ---------------------------------------------------------------------------
// Gate: logits -> top2 -> softmax -> per-expert token lists; also x -> bf16.
// tlist entry packs: tok (bits 0-11) | expert-slot k (bit 15).
// ---------------------------------------------------------------------------
__global__ __launch_bounds__(64) void gate_kernel(
    const float* __restrict__ x, const float* __restrict__ gw,
    const float* __restrict__ gb, __hip_bfloat16* __restrict__ xb,
    int* __restrict__ counts, int* __restrict__ tlist, float* __restrict__ plist)
{
    const int tok = blockIdx.x;
    const int l   = threadIdx.x;
    const float* xr = x + (size_t)tok * DIM;

    float part[NE];
#pragma unroll
    for (int e = 0; e < NE; e++) part[e] = 0.f;

#pragma unroll
    for (int i = 0; i < DIM / 64; i++) {
        int d = i * 64 + l;
        float xv = xr[d];
        xb[(size_t)tok * DIM + d] = __float2bfloat16(xv);
        const float4* g4 = (const float4*)(gw + (size_t)d * NE);
        float4 a = g4[0], b = g4[1];
        part[0] += xv * a.x; part[1] += xv * a.y;
        part[2] += xv * a.z; part[3] += xv * a.w;
        part[4] += xv * b.x; part[5] += xv * b.y;
        part[6] += xv * b.z; part[7] += xv * b.w;
    }
#pragma unroll
    for (int off = 32; off > 0; off >>= 1) {
#pragma unroll
        for (int e = 0; e < NE; e++) part[e] += __shfl_xor(part[e], off, 64);
    }
    if (l == 0) {
        float lg[NE];
#pragma unroll
        for (int e = 0; e < NE; e++) lg[e] = part[e] + gb[e];
        int i0 = 0;
#pragma unroll
        for (int e = 1; e < NE; e++) if (lg[e] > lg[i0]) i0 = e;   // lowest idx on tie
        int i1 = (i0 == 0) ? 1 : 0;
#pragma unroll
        for (int e = 0; e < NE; e++) if (e != i0 && lg[e] > lg[i1]) i1 = e;
        float t  = expf(lg[i1] - lg[i0]);
        float p0 = 1.f / (1.f + t);
        float p1 = t / (1.f + t);
        int pos0 = atomicAdd(&counts[i0], 1);
        tlist[i0 * CAP + pos0] = tok;              plist[i0 * CAP + pos0] = p0;
        int pos1 = atomicAdd(&counts[i1], 1);
        tlist[i1 * CAP + pos1] = tok | (1 << 15);  plist[i1 * CAP + pos1] = p1;
    }
}

// ---------------------------------------------------------------------------
// finalize: prefix-sum bases + build global task lists (expert-major,
// rb-major inner).
// ---------------------------------------------------------------------------
__global__ void finalize_kernel(const int* __restrict__ counts, int* __restrict__ base,
                                int* __restrict__ task1, int* __restrict__ task2,
                                int* __restrict__ ntasks)
{
    __shared__ int stc[NE], so1[NE], so2[NE];
    if (threadIdx.x == 0) {
        int acc = 0, o1 = 0, o2 = 0;
        for (int e = 0; e < NE; e++) {
            base[e] = acc; acc += counts[e];
            int tc = (counts[e] + 255) >> 8;
            stc[e] = tc; so1[e] = o1; so2[e] = o2;
            o1 += tc * 16; o2 += tc * 16;
        }
        base[NE] = acc;
        ntasks[0] = o1; ntasks[1] = o2;
    }
    __syncthreads();
    for (int e = 0; e < NE; e++) {
        int tc = stc[e];
        for (int i = threadIdx.x; i < tc * 16; i += 64) {
            int rb = i >> 4, cb = i & 15;
            task1[so1[e] + i] = (e << 16) | (rb << 8) | cb;
        }
        for (int i = threadIdx.x; i < tc * 16; i += 64) {
            int rb = i >> 4, c = i & 15;      // c = cb*4+sp
            task2[so2[e] + i] = (e << 16) | (rb << 8) | c;
        }
    }
}

// ---------------------------------------------------------------------------
// Transpose + f32->bf16 convert:  in [E][K][N] f32  ->  out [E][N][K] bf16
// ---------------------------------------------------------------------------
__global__ __launch_bounds__(256) void transpose_cvt64(
    const float* __restrict__ in, __hip_bfloat16* __restrict__ outp, int K, int N)
{
    __shared__ ushort tile[64][68];
    const int e  = blockIdx.z;
    const float* src = in + (size_t)e * K * N;
    ushort* dst = (ushort*)outp + (size_t)e * K * N;
    const int k0 = blockIdx.y * 64, n0 = blockIdx.x * 64;
    const int tid = threadIdx.x;

    const int rn4 = (tid & 15) * 4;
    const int rk  = tid >> 4;
#pragma unroll
    for (int p = 0; p < 4; p++) {
        int k = rk + p * 16;
        float4 v = *(const float4*)&src[(size_t)(k0 + k) * N + n0 + rn4];
        tile[k][rn4 + 0] = f2bf(v.x);
        tile[k][rn4 + 1] = f2bf(v.y);
        tile[k][rn4 + 2] = f2bf(v.z);
        tile[k][rn4 + 3] = f2bf(v.w);
    }
    __syncthreads();
    const int wk4 = (tid & 15) * 4;
    const int wn  = tid >> 4;
#pragma unroll
    for (int p = 0; p < 4; p++) {
        int n = wn + p * 16;
        u16x4 u;
        u[0] = tile[wk4 + 0][n];
        u[1] = tile[wk4 + 1][n];
        u[2] = tile[wk4 + 2][n];
        u[3] = tile[wk4 + 3][n];
        *(u16x4*)&dst[(size_t)(n0 + n) * K + k0 + wk4] = u;
    }
}

// ===========================================================================
// 256x256 8-phase grouped GEMM core (BM=BN=256, BK=64, 8 waves 2Mx4N).
// R10 ablation: skeleton <=3.3K cy/tile, +L2-staging 4.46K @ 52% MfmaUtil,
// +real-mem <=6.6K. Production overhead was the epilogue (fixed in R12 via
// LDS-restage coalesced stores).
// ===========================================================================

#define AOFFc(d,s) (((d)*2+(s))*8192)
#define BOFFc(d,s) (32768 + ((d)*2+(s))*8192)

#define MFMA_CL(nj0, nj1)                                                    \
    _Pragma("unroll")                                                        \
    for (int mi = 0; mi < 8; mi++) {                                         \
        acc[mi][nj0] = MFMA16(af[mi], bf##nj0, acc[mi][nj0]);                \
        acc[mi][nj1] = MFMA16(af[mi], bf##nj1, acc[mi][nj1]);                \
    }

#define GEMM_CORE(NT, srcA0, srcA1, srcB0, srcB1)                            \
    f32x4 acc[8][4];                                                         \
    _Pragma("unroll")                                                        \
    for (int i = 0; i < 8; i++)                                              \
        _Pragma("unroll")                                                    \
        for (int j = 0; j < 4; j++) acc[i][j] = (f32x4){0.f,0.f,0.f,0.f};    \
    const int a0 = (wr * 128 + lm) * 32 + rch;                               \
    const int b0 = (wc * 64 + lm) * 32 + rch;                                \
    gll16(srcA0,      &lds[AOFFc(0,0) + w*512]);                             \
    gll16(srcA1,      &lds[AOFFc(0,0) + 4096 + w*512]);                      \
    gll16(srcB0,      &lds[BOFFc(0,0) + w*512]);                             \
    gll16(srcB1,      &lds[BOFFc(0,0) + 4096 + w*512]);                      \
    gll16(srcA0 + 32, &lds[AOFFc(0,1) + w*512]);                             \
    gll16(srcA1 + 32, &lds[AOFFc(0,1) + 4096 + w*512]);                      \
    gll16(srcB0 + 32, &lds[BOFFc(0,1) + w*512]);                             \
    gll16(srcB1 + 32, &lds[BOFFc(0,1) + 4096 + w*512]);                      \
    asm volatile("s_waitcnt vmcnt(4)" ::: "memory");                         \
    gll16(srcA0 + 64, &lds[AOFFc(1,0) + w*512]);                             \
    gll16(srcA1 + 64, &lds[AOFFc(1,0) + 4096 + w*512]);                      \
    gll16(srcB0 + 64, &lds[BOFFc(1,0) + w*512]);                             \
    gll16(srcB1 + 64, &lds[BOFFc(1,0) + 4096 + w*512]);                      \
    gll16(srcA0 + 96, &lds[AOFFc(1,1) + w*512]);                             \
    gll16(srcA1 + 96, &lds[AOFFc(1,1) + 4096 + w*512]);                      \
    asm volatile("s_waitcnt vmcnt(6)" ::: "memory");                         \
    __builtin_amdgcn_s_barrier();                                            \
    _Pragma("unroll 1")                                                      \
    for (int t = 0; t < NT; t++) {                                           \
        const int d   = t & 1;                                               \
        const int aof  = d * 16384,        bof  = 32768 + d * 16384;         \
        const int bofN = 32768 + (d^1) * 16384;                              \
        bf16x8 af[8]; bf16x8 bf0, bf1, bf2, bf3;                             \
        _Pragma("unroll")                                                    \
        for (int mi = 0; mi < 8; mi++)                                       \
            af[mi] = *(const bf16x8*)&lds[aof + a0 + mi*512];                \
        bf0 = *(const bf16x8*)&lds[bof + b0];                                \
        bf1 = *(const bf16x8*)&lds[bof + b0 + 512];                          \
        if (t + 1 < NT) {                                                    \
            size_t ko = (size_t)(t+1)*64 + 32;                               \
            gll16(srcB0 + ko, &lds[bofN + 8192 + w*512]);                    \
            gll16(srcB1 + ko, &lds[bofN + 8192 + 4096 + w*512]);             \
        }                                                                    \
        __builtin_amdgcn_s_barrier();                                        \
        __builtin_amdgcn_s_setprio(1);                                       \
        MFMA_CL(0, 1)                                                        \
        __builtin_amdgcn_s_setprio(0);                                       \
        __builtin_amdgcn_s_barrier();                                        \
        bf2 = *(const bf16x8*)&lds[bof + b0 + 1024];                         \
        bf3 = *(const bf16x8*)&lds[bof + b0 + 1536];                         \
        if (t + 2 < NT) {                                                    \
            size_t ko = (size_t)(t+2)*64;                                    \
            gll16(srcA0 + ko, &lds[aof + w*512]);                            \
            gll16(srcA1 + ko, &lds[aof + 4096 + w*512]);                     \
        }                                                                    \
        __builtin_amdgcn_s_barrier();                                        \
        __builtin_amdgcn_s_setprio(1);                                       \
        MFMA_CL(2, 3)                                                        \
        __builtin_amdgcn_s_setprio(0);                                       \
        __builtin_amdgcn_s_barrier();                                        \
        _Pragma("unroll")                                                    \
        for (int mi = 0; mi < 8; mi++)                                       \
            af[mi] = *(const bf16x8*)&lds[aof + 8192 + a0 + mi*512];         \
        bf0 = *(const bf16x8*)&lds[bof + 8192 + b0];                         \
        bf1 = *(const bf16x8*)&lds[bof + 8192 + b0 + 512];                   \
        if (t + 2 < NT) {                                                    \
            size_t ko = (size_t)(t+2)*64;                                    \
            gll16(srcB0 + ko, &lds[bof + w*512]);                            \
            gll16(srcB1 + ko, &lds[bof + 4096 + w*512]);                     \
        }                                                                    \
        __builtin_amdgcn_s_barrier();                                        \
        __builtin_amdgcn_s_setprio(1);                                       \
        MFMA_CL(0, 1)                                                        \
        __builtin_amdgcn_s_setprio(0);                                       \
        __builtin_amdgcn_s_barrier();                                        \
        bf2 = *(const bf16x8*)&lds[bof + 8192 + b0 + 1024];                  \
        bf3 = *(const bf16x8*)&lds[bof + 8192 + b0 + 1536];                  \
        if (t + 2 < NT) {                                                    \
            size_t ko = (size_t)(t+2)*64 + 32;                               \
            gll16(srcA0 + ko, &lds[aof + 8192 + w*512]);                     \
            gll16(srcA1 + ko, &lds[aof + 8192 + 4096 + w*512]);              \
        }                                                                    \
        __builtin_amdgcn_s_barrier();                                        \
        __builtin_amdgcn_s_setprio(1);                                       \
        MFMA_CL(2, 3)                                                        \
        __builtin_amdgcn_s_setprio(0);                                       \
        if (t < NT - 2) { asm volatile("s_waitcnt vmcnt(6)" ::: "memory"); } \
        else            { asm volatile("s_waitcnt vmcnt(0)" ::: "memory"); } \
        __builtin_amdgcn_s_barrier();                                        \
    }

// Common per-thread index setup
#define CORE_IDX                                                             \
    const int tid = threadIdx.x;                                             \
    const int l = tid & 63, w = tid >> 6;                                    \
    const int wr = w >> 2, wc = w & 3;                                       \
    const int lm = l & 15, kg = l >> 4;                                      \
    const int rch = (kg ^ ((lm >> 1) & 3)) * 8;                              \
    const int srow = tid >> 2;                                               \
    const int sch  = tid & 3;                                                \
    const int sc0  = (sch ^ ((srow >> 1) & 3)) * 8;

// ---------------------------------------------------------------------------
// FFN pass 1 (global dynamic ticket):  H = gelu( gather(xb) @ w1t^T + b1 )
// Epilogue: C-tile restaged through LDS (256x256 bf16 = 128KB exactly);
// bank-spread via col ^ (row&12)<<2; output = 16 coalesced 16B stores/thread
// (32 lanes = one full 512B row). Fixes R11's 2x write-amp (124MB for 64MB H)
// from 128 scalar 2B stores/thread.
// ---------------------------------------------------------------------------
__global__ __launch_bounds__(512, 1) void ffn1_kernel(
    const __hip_bfloat16* __restrict__ xb, const __hip_bfloat16* __restrict__ w1t,
    const float* __restrict__ b1, const int* __restrict__ counts,
    const int* __restrict__ base, const int* __restrict__ tlist,
    const int* __restrict__ task1, const int* __restrict__ ntasks,
    int* __restrict__ ticket, __hip_bfloat16* __restrict__ H)
{
    __shared__ __align__(16) ushort lds[65536];   // 128 KiB
    __shared__ int s_task;
    CORE_IDX
    const int nt1 = ntasks[0];

    for (;;) {
        __syncthreads();                // fences prev task's LDS use
        if (tid == 0) s_task = atomicAdd(ticket, 1);
        __syncthreads();
        const int task = s_task;
        if (task >= nt1) break;
        const int v  = task1[task];
        const int e  = v >> 16, rb = (v >> 8) & 255, cb = v & 255;
        const int ne = counts[e];
        const int hb = base[e];

        const int rA0g = rb * 256 + srow;
        const int rA1g = rA0g + 128;
        const int tok0 = tlist[e * CAP + (rA0g < ne ? rA0g : ne - 1)] & 0xFFF;
        const int tok1 = tlist[e * CAP + (rA1g < ne ? rA1g : ne - 1)] & 0xFFF;
        const ushort* srcA0 = (const ushort*)xb + (size_t)tok0 * DIM + sc0;
        const ushort* srcA1 = (const ushort*)xb + (size_t)tok1 * DIM + sc0;
        const ushort* srcB0 = (const ushort*)w1t + ((size_t)e * HID + cb * 256 + srow) * DIM + sc0;
        const ushort* srcB1 = srcB0 + (size_t)128 * DIM;

        GEMM_CORE(16, srcA0, srcA1, srcB0, srcB1)

        // --- epilogue: bias + GELU -> LDS restage -> coalesced 16B stores ---
#pragma unroll
        for (int nj = 0; nj < 4; nj++) {
            int col = wc * 64 + nj * 16 + lm;
            float bias = b1[e * HID + cb * 256 + col];
#pragma unroll
            for (int mi = 0; mi < 8; mi++) {
#pragma unroll
                for (int jj = 0; jj < 4; jj++) {
                    int row = wr * 128 + mi * 16 + kg * 4 + jj;
                    float vv = acc[mi][nj][jj] + bias;
                    vv = 0.5f * vv * (1.0f + erff(vv * 0.70710678118654752f));
                    lds[row * 256 + (col ^ ((row & 12) << 2))] = f2bf(vv);
                }
            }
        }
        __syncthreads();
#pragma unroll
        for (int pch = 0; pch < 16; pch++) {
            int c   = pch * 512 + tid;
            int row = c >> 5, seg = c & 31;
            int r   = rb * 256 + row;
            if (r < ne) {
                int pseg = seg ^ ((row & 12) >> 1);
                bf16x8 vv8 = *(const bf16x8*)&lds[row * 256 + pseg * 8];
                *(bf16x8*)((ushort*)H + (size_t)(hb + r) * HID + cb * 256 + seg * 8) = vv8;
            }
        }
    }
}

// ---------------------------------------------------------------------------
// FFN pass 2 (global dynamic ticket, split-K=4, no atomics):
// per-slot Y writes, same LDS-restage coalesced epilogue (p and bias folded
// before the bf16 pack — numerics identical to R11).
// ---------------------------------------------------------------------------
__global__ __launch_bounds__(512, 1) void ffn2_kernel(
    const __hip_bfloat16* __restrict__ H, const __hip_bfloat16* __restrict__ w2t,
    const float* __restrict__ b2, const int* __restrict__ counts,
    const int* __restrict__ base, const int* __restrict__ tlist,
    const float* __restrict__ plist, const int* __restrict__ task2,
    const int* __restrict__ ntasks, int* __restrict__ ticket,
    __hip_bfloat16* __restrict__ Y)
{
    __shared__ __align__(16) ushort lds[65536];   // 128 KiB
    __shared__ int s_task;
    CORE_IDX
    const int nt2 = ntasks[1];

    for (;;) {
        __syncthreads();
        if (tid == 0) s_task = atomicAdd(ticket, 1);
        __syncthreads();
        const int task = s_task;
        if (task >= nt2) break;
        const int v  = task2[task];
        const int e  = v >> 16, rb = (v >> 8) & 255;
        const int c  = v & 255;
        const int cb = c >> 2, sp = c & 3;
        const int ne = counts[e];
        const int hb = base[e];

        const int rA0g = rb * 256 + srow;
        const int rA1g = rA0g + 128;
        const int hr0  = hb + (rA0g < ne ? rA0g : ne - 1);
        const int hr1  = hb + (rA1g < ne ? rA1g : ne - 1);
        const size_t ko0 = (size_t)sp * KSP;
        const ushort* srcA0 = (const ushort*)H + (size_t)hr0 * HID + ko0 + sc0;
        const ushort* srcA1 = (const ushort*)H + (size_t)hr1 * HID + ko0 + sc0;
        const ushort* srcB0 = (const ushort*)w2t + ((size_t)e * DIM + cb * 256 + srow) * HID + ko0 + sc0;
        const ushort* srcB1 = srcB0 + (size_t)128 * HID;

        GEMM_CORE(16, srcA0, srcA1, srcB0, srcB1)

        // --- epilogue: (+bias)*p -> LDS restage -> coalesced 16B stores ---
#pragma unroll
        for (int nj = 0; nj < 4; nj++) {
            int col = wc * 64 + nj * 16 + lm;
            float bias = (sp == 0) ? b2[e * DIM + cb * 256 + col] : 0.f;
#pragma unroll
            for (int mi = 0; mi < 8; mi++) {
#pragma unroll
                for (int jj = 0; jj < 4; jj++) {
                    int row = wr * 128 + mi * 16 + kg * 4 + jj;
                    int r   = rb * 256 + row;
                    float p = plist[e * CAP + (r < ne ? r : ne - 1)];
                    float vv = (acc[mi][nj][jj] + bias) * p;
                    lds[row * 256 + (col ^ ((row & 12) << 2))] = f2bf(vv);
                }
            }
        }
        __syncthreads();
#pragma unroll
        for (int pch = 0; pch < 16; pch++) {
            int cch = pch * 512 + tid;
            int row = cch >> 5, seg = cch & 31;
            int r   = rb * 256 + row;
            if (r < ne) {
                int tv  = tlist[e * CAP + r];
                int tok = tv & 0xFFF, kk = tv >> 15;
                int pseg = seg ^ ((row & 12) >> 1);
                bf16x8 vv8 = *(const bf16x8*)&lds[row * 256 + pseg * 8];
                *(bf16x8*)((ushort*)Y + ((size_t)(kk * 4 + sp) * T_TOKENS + tok) * DIM
                           + cb * 256 + seg * 8) = vv8;
            }
        }
    }
}

// ---------------------------------------------------------------------------
// Reduce: out[t][d] = sum of 8 slots (fixed order -> bitwise deterministic).
// ---------------------------------------------------------------------------
__global__ __launch_bounds__(256) void reduce_kernel(
    const __hip_bfloat16* __restrict__ Y, float* __restrict__ out)
{
    const size_t i = ((size_t)blockIdx.x * 256 + threadIdx.x) * 8;
    float s[8];
#pragma unroll
    for (int j = 0; j < 8; j++) s[j] = 0.f;
#pragma unroll
    for (int sl = 0; sl < 8; sl++) {
        bf16x8 v = *(const bf16x8*)((const ushort*)Y + (size_t)sl * T_TOKENS * DIM + i);
#pragma unroll
        for (int j = 0; j < 8; j++) {
            union { unsigned int ui; float f; } cv;
            cv.ui = ((unsigned int)(ushort)v[j]) << 16;
            s[j] += cv.f;
        }
    }
#pragma unroll
    for (int j = 0; j < 8; j++) out[i + j] = s[j];
}

// ---------------------------------------------------------------------------
extern "C" void kernel_launch(void* const* d_in, const int* in_sizes, int n_in,
                              void* d_out, int out_size, void* d_ws, size_t ws_size,
                              hipStream_t stream)
{
    const float* x  = (const float*)d_in[0];
    const float* gw = (const float*)d_in[1];
    const float* gb = (const float*)d_in[2];
    const float* w1 = (const float*)d_in[3];
    const float* b1 = (const float*)d_in[4];
    const float* w2 = (const float*)d_in[5];
    const float* b2 = (const float*)d_in[6];
    float* out = (float*)d_out;

    // workspace carve (bytes)
    char* ws = (char*)d_ws;
    __hip_bfloat16* w1t = (__hip_bfloat16*)(ws);                    // 67108864
    __hip_bfloat16* w2t = (__hip_bfloat16*)(ws + 67108864);         // 67108864
    __hip_bfloat16* Hb  = (__hip_bfloat16*)(ws + 134217728);        // 67108864
    __hip_bfloat16* xb  = (__hip_bfloat16*)(ws + 201326592);        // 8388608
    int*   tlist  = (int*)  (ws + 209715200);                       // 131072
    float* plist  = (float*)(ws + 209846272);                       // 131072
    int*   counts = (int*)  (ws + 209977344);                       // 64
    int*   basep  = (int*)  (ws + 209977408);                       // 64
    int*   ntasks = (int*)  (ws + 209977472);                       // 64
    int*   tickets= (int*)  (ws + 209977536);                       // 64
    int*   task1  = (int*)  (ws + 209977600);                       // 8192
    int*   task2  = (int*)  (ws + 209985792);                       // 8192
    // Y slot buffer reuses w1t's 64 MB: w1t is dead once ffn1 completes
    // (stream-ordered), and Y = 8 slots x 4096 tok x 1024 x bf16 = 64 MB.
    __hip_bfloat16* Y = (__hip_bfloat16*)(ws);

    hipMemsetAsync(counts, 0, 256, stream);   // counts+basep+ntasks+tickets

    gate_kernel<<<T_TOKENS, 64, 0, stream>>>(x, gw, gb, xb, counts, tlist, plist);
    finalize_kernel<<<1, 64, 0, stream>>>(counts, basep, task1, task2, ntasks);

    transpose_cvt64<<<dim3(HID / 64, DIM / 64, NE), 256, 0, stream>>>(w1, w1t, DIM, HID);
    transpose_cvt64<<<dim3(DIM / 64, HID / 64, NE), 256, 0, stream>>>(w2, w2t, HID, DIM);

    ffn1_kernel<<<256, 512, 0, stream>>>(
        xb, w1t, b1, counts, basep, tlist, task1, ntasks, &tickets[0], Hb);
    ffn2_kernel<<<256, 512, 0, stream>>>(
        Hb, w2t, b2, counts, basep, tlist, plist, task2, ntasks, &tickets[1], Y);
    reduce_kernel<<<(T_TOKENS * DIM / 8) / 256, 256, 0, stream>>>(Y, out);
}